// Round 1
// baseline (691.613 us; speedup 1.0000x reference)
//
#include <hip/hip_runtime.h>
#include <math.h>

// Problem constants (from reference setup_inputs)
#define BB   8
#define HH   32
#define KVHH 8
#define DD   128
#define PSZ  16
#define LMAX 4096
#define CHUNK 512
#define NCHUNK (LMAX / CHUNK)   // 8

// per-row strides in the paged cache (floats)
// cache shape: (pages, 2, KVH, PAGE_SIZE, D)
#define PAGE_STRIDE (2 * KVHH * PSZ * DD)   // 32768
#define KV_OFFSET   (KVHH * PSZ * DD)       // 16384 (K -> V)
#define HEAD_STRIDE (PSZ * DD)              // 2048

// Partial kernel: grid = B*H*NCHUNK blocks, 256 threads (8 half-waves of 32).
// Each block handles one chunk of <=512 sparse rows for one (b,h), producing
// a partial online-softmax state (m, l, acc[128]) in workspace.
__global__ __launch_bounds__(256) void attn_partial(
    const float* __restrict__ q,
    const float* __restrict__ cache,
    const int*   __restrict__ indptr,
    const int*   __restrict__ pageind,
    const int*   __restrict__ sind,
    const int*   __restrict__ snnz,
    float* __restrict__ ws_m,      // [B*H][NCHUNK]
    float* __restrict__ ws_l,      // [B*H][NCHUNK]
    float* __restrict__ ws_acc)    // [B*H][NCHUNK][D]
{
    const int blk   = blockIdx.x;
    const int chunk = blk % NCHUNK;
    const int bh    = blk / NCHUNK;
    const int b     = bh / HH;
    const int h     = bh % HH;
    const int kvh   = h >> 2;          // groups = H/KVH = 4
    const int tid   = threadIdx.x;

    const int nnz = snnz[bh];
    const int l0  = chunk * CHUNK;

    const int widx = bh * NCHUNK + chunk;

    if (l0 >= nnz) {
        // empty chunk: write neutral partial (ws is poisoned 0xAA each call)
        if (tid == 0) { ws_m[widx] = -1e30f; ws_l[widx] = 0.0f; }
        if (tid < DD) ws_acc[widx * DD + tid] = 0.0f;
        return;
    }
    const int nrows = min(nnz - l0, CHUNK);

    __shared__ unsigned int s_base[CHUNK];
    __shared__ float s_m[8], s_l[8];
    __shared__ float s_acc[8][DD];

    // Phase 1: resolve sparse_ind -> cache row base offsets (coalesced,
    // shortens the dependent-load chain in the hot loop to LDS->global)
    const int indbase = indptr[b];
    const int* si = sind + bh * LMAX + l0;
    for (int i = tid; i < nrows; i += 256) {
        const int idx  = si[i];
        const int pidx = idx >> 4;       // / PAGE_SIZE
        const int off  = idx & 15;       // % PAGE_SIZE
        const int pid  = pageind[indbase + pidx];
        s_base[i] = (unsigned)pid * PAGE_STRIDE + (unsigned)(kvh * HEAD_STRIDE + off * DD);
    }
    __syncthreads();

    // Phase 2: each half-wave (32 lanes) streams rows; float4 per lane covers
    // the full 128-float row (512 B contiguous per half-wave).
    const int lane32 = tid & 31;
    const int hw     = tid >> 5;         // 0..7

    const float4 q4 = *(const float4*)(q + bh * DD + lane32 * 4);
    const float cscale = 0.08838834764831845f * 1.4426950408889634f; // 1/sqrt(128) * log2(e)

    float m = -1e30f, lsum = 0.0f;
    float4 acc = make_float4(0.f, 0.f, 0.f, 0.f);

    for (int i = hw; i < nrows; i += 8) {
        const unsigned base = s_base[i];
        const float* kp = cache + base + lane32 * 4;
        const float4 k = *(const float4*)kp;
        const float4 v = *(const float4*)(kp + KV_OFFSET);

        float s = k.x * q4.x + k.y * q4.y + k.z * q4.z + k.w * q4.w;
        s += __shfl_xor(s, 16);
        s += __shfl_xor(s, 8);
        s += __shfl_xor(s, 4);
        s += __shfl_xor(s, 2);
        s += __shfl_xor(s, 1);

        const float t    = s * cscale;            // score in log2 domain
        const float mn   = fmaxf(m, t);
        const float corr = exp2f(m - mn);
        const float p    = exp2f(t - mn);
        lsum = lsum * corr + p;
        acc.x = acc.x * corr + p * v.x;
        acc.y = acc.y * corr + p * v.y;
        acc.z = acc.z * corr + p * v.z;
        acc.w = acc.w * corr + p * v.w;
        m = mn;
    }

    // Merge the 8 half-wave partials within the block
    if (lane32 == 0) { s_m[hw] = m; s_l[hw] = lsum; }
    *(float4*)&s_acc[hw][lane32 * 4] = acc;
    __syncthreads();

    if (tid < DD) {
        float M = s_m[0];
        #pragma unroll
        for (int i = 1; i < 8; i++) M = fmaxf(M, s_m[i]);
        float tot = 0.f, a = 0.f;
        #pragma unroll
        for (int i = 0; i < 8; i++) {
            const float f = exp2f(s_m[i] - M);
            tot += s_l[i] * f;
            a   += s_acc[i][tid] * f;
        }
        ws_acc[widx * DD + tid] = a;
        if (tid == 0) { ws_m[widx] = M; ws_l[widx] = tot; }
    }
}

// Combine kernel: grid = B*H blocks, 128 threads; merge NCHUNK partials.
__global__ __launch_bounds__(128) void attn_combine(
    const float* __restrict__ ws_m,
    const float* __restrict__ ws_l,
    const float* __restrict__ ws_acc,
    float* __restrict__ out)
{
    const int bh = blockIdx.x;
    const int d  = threadIdx.x;

    float M = -1e30f;
    #pragma unroll
    for (int i = 0; i < NCHUNK; i++) M = fmaxf(M, ws_m[bh * NCHUNK + i]);

    float tot = 0.f, a = 0.f;
    #pragma unroll
    for (int i = 0; i < NCHUNK; i++) {
        const float f = exp2f(ws_m[bh * NCHUNK + i] - M);
        tot += ws_l[bh * NCHUNK + i] * f;
        a   += ws_acc[(bh * NCHUNK + i) * DD + d] * f;
    }
    out[bh * DD + d] = a / tot;
}

extern "C" void kernel_launch(void* const* d_in, const int* in_sizes, int n_in,
                              void* d_out, int out_size, void* d_ws, size_t ws_size,
                              hipStream_t stream) {
    const float* q      = (const float*)d_in[0];
    const float* cache  = (const float*)d_in[1];
    const int*   indptr = (const int*)d_in[2];
    const int*   pgind  = (const int*)d_in[3];
    const int*   sind   = (const int*)d_in[4];
    const int*   snnz   = (const int*)d_in[5];
    float* out = (float*)d_out;

    // workspace layout: m[256*8], l[256*8], acc[256*8*128]  (~1.04 MB)
    float* ws_m   = (float*)d_ws;
    float* ws_l   = ws_m + BB * HH * NCHUNK;
    float* ws_acc = ws_l + BB * HH * NCHUNK;

    attn_partial<<<dim3(BB * HH * NCHUNK), dim3(256), 0, stream>>>(
        q, cache, indptr, pgind, sind, snnz, ws_m, ws_l, ws_acc);
    attn_combine<<<dim3(BB * HH), dim3(128), 0, stream>>>(
        ws_m, ws_l, ws_acc, out);
}

// Round 2
// 678.286 us; speedup vs baseline: 1.0196x; 1.0196x over previous
//
#include <hip/hip_runtime.h>
#include <math.h>

// Problem constants (from reference setup_inputs)
#define BB   8
#define HH   32
#define KVHH 8
#define DD   128
#define PSZ  16
#define LMAX 4096
#define CHUNK 256
#define NCHUNK (LMAX / CHUNK)   // 16

// cache shape: (pages, 2, KVH, PAGE_SIZE, D), fp32
#define PAGE_STRIDE (2 * KVHH * PSZ * DD)   // 32768 floats
#define KV_OFFSET   (KVHH * PSZ * DD)       // 16384 floats (K -> V)
#define HEAD_STRIDE (PSZ * DD)              // 2048 floats

// Partial kernel: grid = B*H*NCHUNK blocks, 256 threads (8 half-waves of 32).
// Each block handles one chunk of <=256 sparse rows for one (b,h), producing
// a partial online-softmax state (m, l, acc[128]) in workspace.
__global__ __launch_bounds__(256) void attn_partial(
    const float* __restrict__ q,
    const float* __restrict__ cache,
    const int*   __restrict__ indptr,
    const int*   __restrict__ pageind,
    const int*   __restrict__ sind,
    const int*   __restrict__ snnz,
    float* __restrict__ ws_m,      // [B*H][NCHUNK]
    float* __restrict__ ws_l,      // [B*H][NCHUNK]
    float* __restrict__ ws_acc)    // [B*H][NCHUNK][D]
{
    const int blk   = blockIdx.x;
    const int chunk = blk % NCHUNK;
    const int bh    = blk / NCHUNK;
    const int b     = bh / HH;
    const int h     = bh % HH;
    const int kvh   = h >> 2;          // groups = H/KVH = 4
    const int tid   = threadIdx.x;

    const int nnz = snnz[bh];
    const int l0  = chunk * CHUNK;
    const int widx = bh * NCHUNK + chunk;

    if (l0 >= nnz) {
        if (tid == 0) { ws_m[widx] = -1e30f; ws_l[widx] = 0.0f; }
        if (tid < DD) ws_acc[widx * DD + tid] = 0.0f;
        return;
    }
    const int nrows = min(nnz - l0, CHUNK);

    __shared__ unsigned int s_base[CHUNK];
    __shared__ float s_m[8], s_l[8];
    __shared__ float s_acc[8][DD];

    // Phase 1: resolve sparse_ind -> cache row base offsets (coalesced).
    const int indbase = indptr[b];
    const int* si = sind + bh * LMAX + l0;
    if (tid < nrows) {
        const int idx  = si[tid];
        const int pidx = idx >> 4;       // / PAGE_SIZE
        const int off  = idx & 15;       // % PAGE_SIZE
        const int pid  = pageind[indbase + pidx];
        s_base[tid] = (unsigned)pid * PAGE_STRIDE
                    + (unsigned)(kvh * HEAD_STRIDE + off * DD);
    }
    __syncthreads();

    // Phase 2: each half-wave (32 lanes) streams rows, unrolled x2 with two
    // independent online-softmax states to double memory-level parallelism.
    const int lane32 = tid & 31;
    const int hw     = tid >> 5;         // 0..7

    const float4 q4 = *(const float4*)(q + bh * DD + lane32 * 4);
    const float cscale = 0.08838834764831845f * 1.4426950408889634f; // 1/sqrt(128)*log2(e)

    float  m0 = -1e30f, l0s = 0.0f;
    float  m1 = -1e30f, l1s = 0.0f;
    float4 a0 = make_float4(0.f, 0.f, 0.f, 0.f);
    float4 a1 = make_float4(0.f, 0.f, 0.f, 0.f);

    for (int i = hw; i < nrows; i += 16) {
        const bool has1 = (i + 8) < nrows;
        const unsigned b0 = s_base[i];
        const unsigned b1 = s_base[has1 ? (i + 8) : i];

        const float* kp0 = cache + b0 + lane32 * 4;
        const float* kp1 = cache + b1 + lane32 * 4;
        const float4 k0 = *(const float4*)kp0;
        const float4 v0 = *(const float4*)(kp0 + KV_OFFSET);
        const float4 k1 = *(const float4*)kp1;
        const float4 v1 = *(const float4*)(kp1 + KV_OFFSET);

        float s0 = k0.x * q4.x + k0.y * q4.y + k0.z * q4.z + k0.w * q4.w;
        float s1 = k1.x * q4.x + k1.y * q4.y + k1.z * q4.z + k1.w * q4.w;
        s0 += __shfl_xor(s0, 16);  s1 += __shfl_xor(s1, 16);
        s0 += __shfl_xor(s0, 8);   s1 += __shfl_xor(s1, 8);
        s0 += __shfl_xor(s0, 4);   s1 += __shfl_xor(s1, 4);
        s0 += __shfl_xor(s0, 2);   s1 += __shfl_xor(s1, 2);
        s0 += __shfl_xor(s0, 1);   s1 += __shfl_xor(s1, 1);

        {   // state 0
            const float t    = s0 * cscale;
            const float mn   = fmaxf(m0, t);
            const float corr = exp2f(m0 - mn);
            const float p    = exp2f(t - mn);
            l0s = l0s * corr + p;
            a0.x = a0.x * corr + p * v0.x;
            a0.y = a0.y * corr + p * v0.y;
            a0.z = a0.z * corr + p * v0.z;
            a0.w = a0.w * corr + p * v0.w;
            m0 = mn;
        }
        if (has1) {   // state 1
            const float t    = s1 * cscale;
            const float mn   = fmaxf(m1, t);
            const float corr = exp2f(m1 - mn);
            const float p    = exp2f(t - mn);
            l1s = l1s * corr + p;
            a1.x = a1.x * corr + p * v1.x;
            a1.y = a1.y * corr + p * v1.y;
            a1.z = a1.z * corr + p * v1.z;
            a1.w = a1.w * corr + p * v1.w;
            m1 = mn;
        }
    }

    // Merge the two states of this half-wave
    {
        const float mn = fmaxf(m0, m1);
        const float f0 = exp2f(m0 - mn);
        const float f1 = exp2f(m1 - mn);
        l0s = l0s * f0 + l1s * f1;
        a0.x = a0.x * f0 + a1.x * f1;
        a0.y = a0.y * f0 + a1.y * f1;
        a0.z = a0.z * f0 + a1.z * f1;
        a0.w = a0.w * f0 + a1.w * f1;
        m0 = mn;
    }

    // Merge the 8 half-wave partials within the block
    if (lane32 == 0) { s_m[hw] = m0; s_l[hw] = l0s; }
    *(float4*)&s_acc[hw][lane32 * 4] = a0;
    __syncthreads();

    if (tid < DD) {
        float M = s_m[0];
        #pragma unroll
        for (int i = 1; i < 8; i++) M = fmaxf(M, s_m[i]);
        float tot = 0.f, a = 0.f;
        #pragma unroll
        for (int i = 0; i < 8; i++) {
            const float f = exp2f(s_m[i] - M);
            tot += s_l[i] * f;
            a   += s_acc[i][tid] * f;
        }
        ws_acc[widx * DD + tid] = a;
        if (tid == 0) { ws_m[widx] = M; ws_l[widx] = tot; }
    }
}

// Combine kernel: grid = B*H blocks, 128 threads; merge NCHUNK partials.
__global__ __launch_bounds__(128) void attn_combine(
    const float* __restrict__ ws_m,
    const float* __restrict__ ws_l,
    const float* __restrict__ ws_acc,
    float* __restrict__ out)
{
    const int bh = blockIdx.x;
    const int d  = threadIdx.x;

    float M = -1e30f;
    #pragma unroll
    for (int i = 0; i < NCHUNK; i++) M = fmaxf(M, ws_m[bh * NCHUNK + i]);

    float tot = 0.f, a = 0.f;
    #pragma unroll
    for (int i = 0; i < NCHUNK; i++) {
        const float f = exp2f(ws_m[bh * NCHUNK + i] - M);
        tot += ws_l[bh * NCHUNK + i] * f;
        a   += ws_acc[(bh * NCHUNK + i) * DD + d] * f;
    }
    out[bh * DD + d] = a / tot;
}

extern "C" void kernel_launch(void* const* d_in, const int* in_sizes, int n_in,
                              void* d_out, int out_size, void* d_ws, size_t ws_size,
                              hipStream_t stream) {
    const float* q      = (const float*)d_in[0];
    const float* cache  = (const float*)d_in[1];
    const int*   indptr = (const int*)d_in[2];
    const int*   pgind  = (const int*)d_in[3];
    const int*   sind   = (const int*)d_in[4];
    const int*   snnz   = (const int*)d_in[5];
    float* out = (float*)d_out;

    // workspace layout: m[256*16], l[256*16], acc[256*16*128]  (~2.1 MB)
    float* ws_m   = (float*)d_ws;
    float* ws_l   = ws_m + BB * HH * NCHUNK;
    float* ws_acc = ws_l + BB * HH * NCHUNK;

    attn_partial<<<dim3(BB * HH * NCHUNK), dim3(256), 0, stream>>>(
        q, cache, indptr, pgind, sind, snnz, ws_m, ws_l, ws_acc);
    attn_combine<<<dim3(BB * HH), dim3(128), 0, stream>>>(
        ws_m, ws_l, ws_acc, out);
}